// Round 1
// baseline (2703.644 us; speedup 1.0000x reference)
//
#include <hip/hip_runtime.h>

// Problem constants (from reference)
#define N_VUL  100000
#define N_SRC  50000
#define N_EDGE 500000
#define DIM    128

// ---------------------------------------------------------------------------
// Zeroing kernels (harness poisons d_out / d_ws with 0xAA before every call)
// ---------------------------------------------------------------------------
__global__ void zero_f4_kernel(float4* __restrict__ p, int n4) {
    int i = blockIdx.x * blockDim.x + threadIdx.x;
    if (i < n4) p[i] = make_float4(0.f, 0.f, 0.f, 0.f);
}

__global__ void zero_i_kernel(int* __restrict__ p, int n) {
    int i = blockIdx.x * blockDim.x + threadIdx.x;
    if (i < n) p[i] = 0;
}

// ---------------------------------------------------------------------------
// Pass 1: per-relation in-degree histogram
// ---------------------------------------------------------------------------
__global__ void count_kernel(const int* __restrict__ dst, int* __restrict__ cnt, int n) {
    int i = blockIdx.x * blockDim.x + threadIdx.x;
    if (i < n) atomicAdd(&cnt[dst[i]], 1);
}

// ---------------------------------------------------------------------------
// Pass 2: scale[v] = 1 / (3 * max(cnt,1))  -- folds the /3 relation-mean in
// ---------------------------------------------------------------------------
__global__ void scale_kernel(const int* __restrict__ cnt, float* __restrict__ scale, int n) {
    int i = blockIdx.x * blockDim.x + threadIdx.x;
    if (i < n) {
        int c = cnt[i];
        scale[i] = 1.0f / (3.0f * (float)(c > 0 ? c : 1));
    }
}

// ---------------------------------------------------------------------------
// Pass 3: edge scatter. 32 lanes per edge, float4 per lane (512 B per edge,
// fully coalesced on both gather and scatter). unsafeAtomicAdd guarantees
// native global_atomic_add_f32 (no CAS loop) on gfx950.
// ---------------------------------------------------------------------------
__global__ void edge_kernel(const float* __restrict__ x,
                            const int* __restrict__ src,
                            const int* __restrict__ dst,
                            const float* __restrict__ scale,
                            float* __restrict__ out) {
    long long t = (long long)blockIdx.x * blockDim.x + threadIdx.x;
    int e    = (int)(t >> 5);
    int lane = (int)(t & 31);
    if (e >= N_EDGE) return;

    int s = src[e];
    int d = dst[e];
    float sc = scale[d];

    const float4* xrow = (const float4*)(x + (size_t)s * DIM);
    float4 v = xrow[lane];

    float* o = out + (size_t)d * DIM + lane * 4;
    unsafeAtomicAdd(o + 0, v.x * sc);
    unsafeAtomicAdd(o + 1, v.y * sc);
    unsafeAtomicAdd(o + 2, v.z * sc);
    unsafeAtomicAdd(o + 3, v.w * sc);
}

// ---------------------------------------------------------------------------
extern "C" void kernel_launch(void* const* d_in, const int* in_sizes, int n_in,
                              void* d_out, int out_size, void* d_ws, size_t ws_size,
                              hipStream_t stream) {
    // Input order: x_a, x_b, x_c, src_a, dst_a, src_b, dst_b, src_c, dst_c
    const float* x[3]   = { (const float*)d_in[0], (const float*)d_in[1], (const float*)d_in[2] };
    const int*   src[3] = { (const int*)d_in[3],   (const int*)d_in[5],   (const int*)d_in[7] };
    const int*   dst[3] = { (const int*)d_in[4],   (const int*)d_in[6],   (const int*)d_in[8] };
    float* out = (float*)d_out;

    // Workspace layout: [3*N_VUL ints: counts][3*N_VUL floats: scales] = 2.4 MB
    int*   cnt   = (int*)d_ws;
    float* scale = (float*)d_ws + 3 * N_VUL;

    const int B = 256;

    // Zero output + counts
    int n_out4 = N_VUL * DIM / 4;
    zero_f4_kernel<<<(n_out4 + B - 1) / B, B, 0, stream>>>((float4*)out, n_out4);
    zero_i_kernel<<<(3 * N_VUL + B - 1) / B, B, 0, stream>>>(cnt, 3 * N_VUL);

    // Histogram per relation
    for (int r = 0; r < 3; ++r) {
        count_kernel<<<(N_EDGE + B - 1) / B, B, 0, stream>>>(dst[r], cnt + r * N_VUL, N_EDGE);
    }

    // Inverse scales
    scale_kernel<<<(3 * N_VUL + B - 1) / B, B, 0, stream>>>(cnt, scale, 3 * N_VUL);

    // Edge scatter per relation: 500000 edges * 32 lanes / 256 = 62500 blocks
    long long n_threads = (long long)N_EDGE * 32;
    int n_blocks = (int)((n_threads + B - 1) / B);
    for (int r = 0; r < 3; ++r) {
        edge_kernel<<<n_blocks, B, 0, stream>>>(x[r], src[r], dst[r], scale + r * N_VUL, out);
    }
}

// Round 2
// 491.926 us; speedup vs baseline: 5.4960x; 5.4960x over previous
//
#include <hip/hip_runtime.h>

#define N_VUL  100000
#define N_SRC  50000
#define N_EDGE 500000
#define DIM    128

// ---------------------------------------------------------------------------
// Workspace layout (exactly 2,400,000 B -- proven safe in R1):
//   rp : N_VUL ints  (histogram -> exclusive scan -> after scatter: bucket ENDs)
//   ss : N_EDGE ints (dst-sorted src indices)
// Reused sequentially for each of the 3 relations.
// ---------------------------------------------------------------------------

__global__ void zero_i_kernel(int* __restrict__ p, int n) {
    int i = blockIdx.x * blockDim.x + threadIdx.x;
    if (i < n) p[i] = 0;
}

__global__ void count_kernel(const int* __restrict__ dst, int* __restrict__ cnt, int n) {
    int i = blockIdx.x * blockDim.x + threadIdx.x;
    if (i < n) atomicAdd(&cnt[dst[i]], 1);
}

// In-place exclusive prefix scan of rp[0..n-1]. Single block, 1024 threads,
// int4 per thread -> 4096-element chunks, serial carry across chunks.
__global__ void scan_kernel(int* __restrict__ rp, int n) {
    __shared__ int warp_sums[16];
    __shared__ int s_carry;
    const int tid  = threadIdx.x;
    const int lane = tid & 63;
    const int wid  = tid >> 6;
    if (tid == 0) s_carry = 0;
    __syncthreads();

    for (int base = 0; base < n; base += 4096) {
        int idx = base + tid * 4;
        int4 v = make_int4(0, 0, 0, 0);
        if (idx + 3 < n) {
            v = *(const int4*)(rp + idx);
        } else {
            if (idx + 0 < n) v.x = rp[idx + 0];
            if (idx + 1 < n) v.y = rp[idx + 1];
            if (idx + 2 < n) v.z = rp[idx + 2];
            if (idx + 3 < n) v.w = rp[idx + 3];
        }
        int tsum = v.x + v.y + v.z + v.w;

        // inclusive wave scan of per-thread sums
        int s = tsum;
        #pragma unroll
        for (int off = 1; off < 64; off <<= 1) {
            int t = __shfl_up(s, off);
            if (lane >= off) s += t;
        }
        if (lane == 63) warp_sums[wid] = s;
        __syncthreads();

        if (tid < 16) {
            int ws = warp_sums[tid];
            #pragma unroll
            for (int off = 1; off < 16; off <<= 1) {
                int t = __shfl_up(ws, off);
                if (tid >= off) ws += t;
            }
            warp_sums[tid] = ws;  // inclusive scan of wave totals
        }
        __syncthreads();

        int carry = s_carry;
        int excl  = s - tsum + (wid > 0 ? warp_sums[wid - 1] : 0) + carry;

        int4 o;
        o.x = excl;
        o.y = o.x + v.x;
        o.z = o.y + v.y;
        o.w = o.z + v.z;
        if (idx + 3 < n) {
            *(int4*)(rp + idx) = o;
        } else {
            if (idx + 0 < n) rp[idx + 0] = o.x;
            if (idx + 1 < n) rp[idx + 1] = o.y;
            if (idx + 2 < n) rp[idx + 2] = o.z;
            if (idx + 3 < n) rp[idx + 3] = o.w;
        }
        __syncthreads();  // all lanes have read s_carry & warp_sums
        if (tid == 0) s_carry = carry + warp_sums[15];
        __syncthreads();
    }
}

// Bucket the edges: ss[pos] = src, pos via atomic cursor on rp.
// Afterwards rp[v] == exclusive end of bucket v (begin = rp[v-1] or 0).
__global__ void scatter_kernel(const int* __restrict__ src,
                               const int* __restrict__ dst,
                               int* __restrict__ rp,
                               int* __restrict__ ss, int n) {
    int i = blockIdx.x * blockDim.x + threadIdx.x;
    if (i < n) {
        int d   = dst[i];
        int pos = atomicAdd(&rp[d], 1);
        ss[pos] = src[i];
    }
}

// One 32-lane half-wave per destination row; float4 per lane (= 128 floats).
// Loads up to 32 src ids per vector load, shfl-broadcasts each, accumulates
// x rows in registers, single (non-atomic) write/update of the output row.
template <bool ACC>
__global__ void gather_kernel(const float* __restrict__ x,
                              const int* __restrict__ rp,
                              const int* __restrict__ ss,
                              float* __restrict__ out) {
    int t    = blockIdx.x * blockDim.x + threadIdx.x;
    int v    = t >> 5;
    int lane = t & 31;
    if (v >= N_VUL) return;

    int end = rp[v];
    int beg = (v == 0) ? 0 : rp[v - 1];

    float4 acc = make_float4(0.f, 0.f, 0.f, 0.f);
    for (int base = beg; base < end; base += 32) {
        int j  = base + lane;
        int sv = (j < end) ? ss[j] : 0;
        int m  = end - base;
        if (m > 32) m = 32;
        for (int k = 0; k < m; ++k) {
            int s = __shfl(sv, k, 32);
            const float4* xr = (const float4*)(x + (size_t)s * DIM);
            float4 xv = xr[lane];
            acc.x += xv.x; acc.y += xv.y; acc.z += xv.z; acc.w += xv.w;
        }
    }

    int deg = end - beg;
    float sc = 1.0f / (3.0f * (float)(deg > 0 ? deg : 1));

    float4 res;
    res.x = acc.x * sc; res.y = acc.y * sc;
    res.z = acc.z * sc; res.w = acc.w * sc;

    float4* o = (float4*)(out + (size_t)v * DIM) + lane;
    if (ACC) {
        float4 prev = *o;
        res.x += prev.x; res.y += prev.y; res.z += prev.z; res.w += prev.w;
    }
    *o = res;
}

// ---------------------------------------------------------------------------
extern "C" void kernel_launch(void* const* d_in, const int* in_sizes, int n_in,
                              void* d_out, int out_size, void* d_ws, size_t ws_size,
                              hipStream_t stream) {
    const float* x[3]   = { (const float*)d_in[0], (const float*)d_in[1], (const float*)d_in[2] };
    const int*   src[3] = { (const int*)d_in[3],   (const int*)d_in[5],   (const int*)d_in[7] };
    const int*   dst[3] = { (const int*)d_in[4],   (const int*)d_in[6],   (const int*)d_in[8] };
    float* out = (float*)d_out;

    int* rp = (int*)d_ws;           // N_VUL ints
    int* ss = (int*)d_ws + N_VUL;   // N_EDGE ints

    const int B = 256;
    const int g_node = (N_VUL + B - 1) / B;
    const int g_edge = (N_EDGE + B - 1) / B;
    const int g_gath = (N_VUL * 32 + B - 1) / B;

    for (int r = 0; r < 3; ++r) {
        zero_i_kernel<<<g_node, B, 0, stream>>>(rp, N_VUL);
        count_kernel<<<g_edge, B, 0, stream>>>(dst[r], rp, N_EDGE);
        scan_kernel<<<1, 1024, 0, stream>>>(rp, N_VUL);
        scatter_kernel<<<g_edge, B, 0, stream>>>(src[r], dst[r], rp, ss, N_EDGE);
        if (r == 0)
            gather_kernel<false><<<g_gath, B, 0, stream>>>(x[r], rp, ss, out);
        else
            gather_kernel<true ><<<g_gath, B, 0, stream>>>(x[r], rp, ss, out);
    }
}

// Round 3
// 401.970 us; speedup vs baseline: 6.7260x; 1.2238x over previous
//
#include <hip/hip_runtime.h>

#define N_VUL  100000
#define N_SRC  50000
#define N_EDGE 500000
#define DIM    128

// ===========================================================================
// FUSED PATH (ws >= 7.21 MB):
//   rp   : 3*N_VUL ints   -- concatenated per-relation histograms -> excl scan
//                            -> (after scatter) bucket ENDs
//   ss   : 3*N_EDGE ints  -- (dst,relation)-bucketed src indices
//   bsum : 512 ints       -- per-chunk sums for multi-block scan
// FALLBACK PATH (ws >= 2.4 MB): R2 sequential structure, single-block scan.
// ===========================================================================

__global__ void zero_i_kernel(int* __restrict__ p, int n) {
    int i = blockIdx.x * blockDim.x + threadIdx.x;
    if (i < n) p[i] = 0;
}

// ------------------------- fused (3-relation) kernels ----------------------

__global__ void count3_kernel(const int* __restrict__ d0, const int* __restrict__ d1,
                              const int* __restrict__ d2, int* __restrict__ rp) {
    int i = blockIdx.x * blockDim.x + threadIdx.x;
    if (i >= 3 * N_EDGE) return;
    int r = (i >= 2 * N_EDGE) ? 2 : (i >= N_EDGE) ? 1 : 0;
    int e = i - r * N_EDGE;
    const int* d = (r == 0) ? d0 : (r == 1) ? d1 : d2;
    atomicAdd(&rp[r * N_VUL + d[e]], 1);
}

// Local exclusive scan of each 1024-int chunk; chunk total -> bsum[chunk].
__global__ void scan_local_kernel(int* __restrict__ rp, int* __restrict__ bsum, int n) {
    __shared__ int wsum[4];
    const int tid  = threadIdx.x;          // 256 threads
    const int lane = tid & 63;
    const int wid  = tid >> 6;
    int idx = blockIdx.x * 1024 + tid * 4;

    int4 v = make_int4(0, 0, 0, 0);
    if (idx + 3 < n)      v = *(const int4*)(rp + idx);
    else {
        if (idx + 0 < n) v.x = rp[idx + 0];
        if (idx + 1 < n) v.y = rp[idx + 1];
        if (idx + 2 < n) v.z = rp[idx + 2];
        if (idx + 3 < n) v.w = rp[idx + 3];
    }
    int tsum = v.x + v.y + v.z + v.w;

    int s = tsum;
    #pragma unroll
    for (int off = 1; off < 64; off <<= 1) {
        int t = __shfl_up(s, off);
        if (lane >= off) s += t;
    }
    if (lane == 63) wsum[wid] = s;
    __syncthreads();
    if (tid == 0) {
        int a = 0;
        #pragma unroll
        for (int j = 0; j < 4; ++j) { int t = wsum[j]; wsum[j] = a; a += t; }
        bsum[blockIdx.x] = a;
    }
    __syncthreads();

    int excl = (s - tsum) + wsum[wid];
    int4 o;
    o.x = excl;
    o.y = o.x + v.x;
    o.z = o.y + v.y;
    o.w = o.z + v.z;
    if (idx + 3 < n)      *(int4*)(rp + idx) = o;
    else {
        if (idx + 0 < n) rp[idx + 0] = o.x;
        if (idx + 1 < n) rp[idx + 1] = o.y;
        if (idx + 2 < n) rp[idx + 2] = o.z;
        if (idx + 3 < n) rp[idx + 3] = o.w;
    }
}

// Exclusive scan of bsum[0..nb-1], nb <= 512. Single block of 512 threads.
__global__ void scan_bsum_kernel(int* __restrict__ bsum, int nb) {
    __shared__ int sh[512];
    int tid = threadIdx.x;
    int v = (tid < nb) ? bsum[tid] : 0;
    sh[tid] = v;
    __syncthreads();
    #pragma unroll
    for (int off = 1; off < 512; off <<= 1) {
        int t = 0;
        if (tid >= off) t = sh[tid - off];
        __syncthreads();
        sh[tid] += t;
        __syncthreads();
    }
    if (tid < nb) bsum[tid] = sh[tid] - v;   // inclusive - self = exclusive
}

__global__ void add_off_kernel(int4* __restrict__ rp4, const int* __restrict__ bsum, int n4) {
    int i = blockIdx.x * blockDim.x + threadIdx.x;
    if (i >= n4) return;
    int off = bsum[i >> 8];   // 256 int4s per 1024-int chunk
    int4 v = rp4[i];
    v.x += off; v.y += off; v.z += off; v.w += off;
    rp4[i] = v;
}

__global__ void scatter3_kernel(const int* __restrict__ s0, const int* __restrict__ d0,
                                const int* __restrict__ s1, const int* __restrict__ d1,
                                const int* __restrict__ s2, const int* __restrict__ d2,
                                int* __restrict__ rp, int* __restrict__ ss) {
    int i = blockIdx.x * blockDim.x + threadIdx.x;
    if (i >= 3 * N_EDGE) return;
    int r = (i >= 2 * N_EDGE) ? 2 : (i >= N_EDGE) ? 1 : 0;
    int e = i - r * N_EDGE;
    const int* sp = (r == 0) ? s0 : (r == 1) ? s1 : s2;
    const int* dp = (r == 0) ? d0 : (r == 1) ? d1 : d2;
    int pos = atomicAdd(&rp[r * N_VUL + dp[e]], 1);
    ss[pos] = sp[e];
}

// One 32-lane group per destination row; loops over the 3 relation buckets,
// accumulates each with its own 1/(3*deg) scale, single float4 write per lane.
__global__ void gather3_kernel(const float* __restrict__ x0, const float* __restrict__ x1,
                               const float* __restrict__ x2,
                               const int* __restrict__ rp, const int* __restrict__ ss,
                               float* __restrict__ out) {
    int t    = blockIdx.x * blockDim.x + threadIdx.x;
    int v    = t >> 5;
    int lane = t & 31;
    if (v >= N_VUL) return;

    float4 res = make_float4(0.f, 0.f, 0.f, 0.f);
    #pragma unroll
    for (int r = 0; r < 3; ++r) {
        const float* x = (r == 0) ? x0 : (r == 1) ? x1 : x2;
        int g   = r * N_VUL + v;
        int end = rp[g];
        int beg = (g == 0) ? 0 : rp[g - 1];

        float4 acc = make_float4(0.f, 0.f, 0.f, 0.f);
        for (int base = beg; base < end; base += 32) {
            int j  = base + lane;
            int sv = (j < end) ? ss[j] : 0;
            int m  = end - base;
            if (m > 32) m = 32;
            for (int k = 0; k < m; ++k) {
                int s = __shfl(sv, k, 32);
                const float4* xr = (const float4*)(x + (size_t)s * DIM);
                float4 xv = xr[lane];
                acc.x += xv.x; acc.y += xv.y; acc.z += xv.z; acc.w += xv.w;
            }
        }
        int deg = end - beg;
        float sc = 1.0f / (3.0f * (float)(deg > 0 ? deg : 1));
        res.x += acc.x * sc; res.y += acc.y * sc;
        res.z += acc.z * sc; res.w += acc.w * sc;
    }

    ((float4*)(out + (size_t)v * DIM))[lane] = res;
}

// ------------------------- fallback (R2 sequential) ------------------------

__global__ void count_kernel(const int* __restrict__ dst, int* __restrict__ cnt, int n) {
    int i = blockIdx.x * blockDim.x + threadIdx.x;
    if (i < n) atomicAdd(&cnt[dst[i]], 1);
}

__global__ void scan_kernel(int* __restrict__ rp, int n) {
    __shared__ int warp_sums[16];
    __shared__ int s_carry;
    const int tid  = threadIdx.x;
    const int lane = tid & 63;
    const int wid  = tid >> 6;
    if (tid == 0) s_carry = 0;
    __syncthreads();
    for (int base = 0; base < n; base += 4096) {
        int idx = base + tid * 4;
        int4 v = make_int4(0, 0, 0, 0);
        if (idx + 3 < n) v = *(const int4*)(rp + idx);
        else {
            if (idx + 0 < n) v.x = rp[idx + 0];
            if (idx + 1 < n) v.y = rp[idx + 1];
            if (idx + 2 < n) v.z = rp[idx + 2];
            if (idx + 3 < n) v.w = rp[idx + 3];
        }
        int tsum = v.x + v.y + v.z + v.w;
        int s = tsum;
        #pragma unroll
        for (int off = 1; off < 64; off <<= 1) {
            int t = __shfl_up(s, off);
            if (lane >= off) s += t;
        }
        if (lane == 63) warp_sums[wid] = s;
        __syncthreads();
        if (tid < 16) {
            int ws = warp_sums[tid];
            #pragma unroll
            for (int off = 1; off < 16; off <<= 1) {
                int t = __shfl_up(ws, off);
                if (tid >= off) ws += t;
            }
            warp_sums[tid] = ws;
        }
        __syncthreads();
        int carry = s_carry;
        int excl  = s - tsum + (wid > 0 ? warp_sums[wid - 1] : 0) + carry;
        int4 o;
        o.x = excl; o.y = o.x + v.x; o.z = o.y + v.y; o.w = o.z + v.z;
        if (idx + 3 < n) *(int4*)(rp + idx) = o;
        else {
            if (idx + 0 < n) rp[idx + 0] = o.x;
            if (idx + 1 < n) rp[idx + 1] = o.y;
            if (idx + 2 < n) rp[idx + 2] = o.z;
            if (idx + 3 < n) rp[idx + 3] = o.w;
        }
        __syncthreads();
        if (tid == 0) s_carry = carry + warp_sums[15];
        __syncthreads();
    }
}

__global__ void scatter_kernel(const int* __restrict__ src, const int* __restrict__ dst,
                               int* __restrict__ rp, int* __restrict__ ss, int n) {
    int i = blockIdx.x * blockDim.x + threadIdx.x;
    if (i < n) {
        int pos = atomicAdd(&rp[dst[i]], 1);
        ss[pos] = src[i];
    }
}

template <bool ACC>
__global__ void gather_kernel(const float* __restrict__ x, const int* __restrict__ rp,
                              const int* __restrict__ ss, float* __restrict__ out) {
    int t    = blockIdx.x * blockDim.x + threadIdx.x;
    int v    = t >> 5;
    int lane = t & 31;
    if (v >= N_VUL) return;
    int end = rp[v];
    int beg = (v == 0) ? 0 : rp[v - 1];
    float4 acc = make_float4(0.f, 0.f, 0.f, 0.f);
    for (int base = beg; base < end; base += 32) {
        int j  = base + lane;
        int sv = (j < end) ? ss[j] : 0;
        int m  = end - base;
        if (m > 32) m = 32;
        for (int k = 0; k < m; ++k) {
            int s = __shfl(sv, k, 32);
            const float4* xr = (const float4*)(x + (size_t)s * DIM);
            float4 xv = xr[lane];
            acc.x += xv.x; acc.y += xv.y; acc.z += xv.z; acc.w += xv.w;
        }
    }
    int deg = end - beg;
    float sc = 1.0f / (3.0f * (float)(deg > 0 ? deg : 1));
    float4 res;
    res.x = acc.x * sc; res.y = acc.y * sc; res.z = acc.z * sc; res.w = acc.w * sc;
    float4* o = (float4*)(out + (size_t)v * DIM) + lane;
    if (ACC) {
        float4 prev = *o;
        res.x += prev.x; res.y += prev.y; res.z += prev.z; res.w += prev.w;
    }
    *o = res;
}

// ---------------------------------------------------------------------------
extern "C" void kernel_launch(void* const* d_in, const int* in_sizes, int n_in,
                              void* d_out, int out_size, void* d_ws, size_t ws_size,
                              hipStream_t stream) {
    const float* x[3]   = { (const float*)d_in[0], (const float*)d_in[1], (const float*)d_in[2] };
    const int*   src[3] = { (const int*)d_in[3],   (const int*)d_in[5],   (const int*)d_in[7] };
    const int*   dst[3] = { (const int*)d_in[4],   (const int*)d_in[6],   (const int*)d_in[8] };
    float* out = (float*)d_out;

    const int B = 256;
    const size_t FUSED_WS = (size_t)(3 * N_VUL + 3 * N_EDGE + 512) * sizeof(int); // 7.2 MB

    if (ws_size >= FUSED_WS) {
        int* rp   = (int*)d_ws;                       // 3*N_VUL
        int* ss   = rp + 3 * N_VUL;                   // 3*N_EDGE
        int* bsum = ss + 3 * N_EDGE;                  // 512

        const int n_rp     = 3 * N_VUL;               // 300000
        const int n_chunks = (n_rp + 1023) / 1024;    // 293
        const int n_rp4    = n_rp / 4;                // 75000

        zero_i_kernel<<<(n_rp + B - 1) / B, B, 0, stream>>>(rp, n_rp);
        count3_kernel<<<(3 * N_EDGE + B - 1) / B, B, 0, stream>>>(dst[0], dst[1], dst[2], rp);
        scan_local_kernel<<<n_chunks, B, 0, stream>>>(rp, bsum, n_rp);
        scan_bsum_kernel<<<1, 512, 0, stream>>>(bsum, n_chunks);
        add_off_kernel<<<(n_rp4 + B - 1) / B, B, 0, stream>>>((int4*)rp, bsum, n_rp4);
        scatter3_kernel<<<(3 * N_EDGE + B - 1) / B, B, 0, stream>>>(
            src[0], dst[0], src[1], dst[1], src[2], dst[2], rp, ss);
        gather3_kernel<<<(N_VUL * 32 + B - 1) / B, B, 0, stream>>>(
            x[0], x[1], x[2], rp, ss, out);
    } else {
        // R2 fallback: sequential per-relation, 2.4 MB ws
        int* rp = (int*)d_ws;
        int* ss = rp + N_VUL;
        const int g_node = (N_VUL + B - 1) / B;
        const int g_edge = (N_EDGE + B - 1) / B;
        const int g_gath = (N_VUL * 32 + B - 1) / B;
        for (int r = 0; r < 3; ++r) {
            zero_i_kernel<<<g_node, B, 0, stream>>>(rp, N_VUL);
            count_kernel<<<g_edge, B, 0, stream>>>(dst[r], rp, N_EDGE);
            scan_kernel<<<1, 1024, 0, stream>>>(rp, N_VUL);
            scatter_kernel<<<g_edge, B, 0, stream>>>(src[r], dst[r], rp, ss, N_EDGE);
            if (r == 0) gather_kernel<false><<<g_gath, B, 0, stream>>>(x[r], rp, ss, out);
            else        gather_kernel<true ><<<g_gath, B, 0, stream>>>(x[r], rp, ss, out);
        }
    }
}

// Round 4
// 357.313 us; speedup vs baseline: 7.5666x; 1.1250x over previous
//
#include <hip/hip_runtime.h>

#define N_VUL  100000
#define N_SRC  50000
#define N_EDGE 500000
#define DIM    128

// ===========================================================================
// TIER A (ws >= 45.6 MB): bf16-compressed gather.
//   rp   : 3*N_VUL ints       histograms -> excl scan -> bucket ENDs
//   ss   : 3*N_EDGE ints      (dst,relation)-bucketed src ids
//   bsum : 512 ints           multi-block scan partials
//   xb   : 3*N_SRC*DIM ushort bf16 copies of x_a,x_b,x_c
// TIER B (ws >= 7.21 MB): R3 fused f32 path.
// TIER C (ws >= 2.4 MB):  R2 sequential path.
// ===========================================================================

__device__ __forceinline__ unsigned short f2bf(float f) {
    unsigned u = __float_as_uint(f);
    unsigned r = (u + 0x7FFFu + ((u >> 16) & 1u)) >> 16;   // RNE
    return (unsigned short)r;
}
__device__ __forceinline__ float bf2f(unsigned short h) {
    return __uint_as_float(((unsigned)h) << 16);
}

__global__ void zero_i_kernel(int* __restrict__ p, int n) {
    int i = blockIdx.x * blockDim.x + threadIdx.x;
    if (i < n) p[i] = 0;
}

// ------------------------- shared build kernels ----------------------------

// Local exclusive scan of each 1024-int chunk; chunk total -> bsum[chunk].
__global__ void scan_local_kernel(int* __restrict__ rp, int* __restrict__ bsum, int n) {
    __shared__ int wsum[4];
    const int tid  = threadIdx.x;          // 256 threads
    const int lane = tid & 63;
    const int wid  = tid >> 6;
    int idx = blockIdx.x * 1024 + tid * 4;

    int4 v = make_int4(0, 0, 0, 0);
    if (idx + 3 < n)      v = *(const int4*)(rp + idx);
    else {
        if (idx + 0 < n) v.x = rp[idx + 0];
        if (idx + 1 < n) v.y = rp[idx + 1];
        if (idx + 2 < n) v.z = rp[idx + 2];
        if (idx + 3 < n) v.w = rp[idx + 3];
    }
    int tsum = v.x + v.y + v.z + v.w;

    int s = tsum;
    #pragma unroll
    for (int off = 1; off < 64; off <<= 1) {
        int t = __shfl_up(s, off);
        if (lane >= off) s += t;
    }
    if (lane == 63) wsum[wid] = s;
    __syncthreads();
    if (tid == 0) {
        int a = 0;
        #pragma unroll
        for (int j = 0; j < 4; ++j) { int t = wsum[j]; wsum[j] = a; a += t; }
        bsum[blockIdx.x] = a;
    }
    __syncthreads();

    int excl = (s - tsum) + wsum[wid];
    int4 o;
    o.x = excl; o.y = o.x + v.x; o.z = o.y + v.y; o.w = o.z + v.z;
    if (idx + 3 < n)      *(int4*)(rp + idx) = o;
    else {
        if (idx + 0 < n) rp[idx + 0] = o.x;
        if (idx + 1 < n) rp[idx + 1] = o.y;
        if (idx + 2 < n) rp[idx + 2] = o.z;
        if (idx + 3 < n) rp[idx + 3] = o.w;
    }
}

__global__ void scan_bsum_kernel(int* __restrict__ bsum, int nb) {
    __shared__ int sh[512];
    int tid = threadIdx.x;
    int v = (tid < nb) ? bsum[tid] : 0;
    sh[tid] = v;
    __syncthreads();
    #pragma unroll
    for (int off = 1; off < 512; off <<= 1) {
        int t = 0;
        if (tid >= off) t = sh[tid - off];
        __syncthreads();
        sh[tid] += t;
        __syncthreads();
    }
    if (tid < nb) bsum[tid] = sh[tid] - v;
}

__global__ void add_off_kernel(int4* __restrict__ rp4, const int* __restrict__ bsum, int n4) {
    int i = blockIdx.x * blockDim.x + threadIdx.x;
    if (i >= n4) return;
    int off = bsum[i >> 8];
    int4 v = rp4[i];
    v.x += off; v.y += off; v.z += off; v.w += off;
    rp4[i] = v;
}

__global__ void scatter3_kernel(const int* __restrict__ s0, const int* __restrict__ d0,
                                const int* __restrict__ s1, const int* __restrict__ d1,
                                const int* __restrict__ s2, const int* __restrict__ d2,
                                int* __restrict__ rp, int* __restrict__ ss) {
    int i = blockIdx.x * blockDim.x + threadIdx.x;
    if (i >= 3 * N_EDGE) return;
    int r = (i >= 2 * N_EDGE) ? 2 : (i >= N_EDGE) ? 1 : 0;
    int e = i - r * N_EDGE;
    const int* sp = (r == 0) ? s0 : (r == 1) ? s1 : s2;
    const int* dp = (r == 0) ? d0 : (r == 1) ? d1 : d2;
    int pos = atomicAdd(&rp[r * N_VUL + dp[e]], 1);
    ss[pos] = sp[e];
}

// ------------------------- TIER A kernels ----------------------------------

#define CVT_Q      (N_SRC * DIM / 4)           // 1.6M float4 per relation
#define CVT_BLOCKS (3 * CVT_Q / 256)           // 18750 (exact)
#define CNT_BLOCKS ((3 * N_EDGE + 255) / 256)  // 5860

// Heterogeneous dispatch: first CVT_BLOCKS convert f32->bf16 (BW-bound),
// remaining CNT_BLOCKS do the degree histogram (atomic-bound). Independent.
__global__ void count3cvt_kernel(const float4* __restrict__ x0, const float4* __restrict__ x1,
                                 const float4* __restrict__ x2, ushort4* __restrict__ xb4,
                                 const int* __restrict__ d0, const int* __restrict__ d1,
                                 const int* __restrict__ d2, int* __restrict__ rp) {
    int b = blockIdx.x;
    if (b < CVT_BLOCKS) {
        int i = b * 256 + threadIdx.x;         // < 4.8M exactly
        int r = i / CVT_Q;
        int e = i - r * CVT_Q;
        float4 v = ((r == 0) ? x0 : (r == 1) ? x1 : x2)[e];
        ushort4 o;
        o.x = f2bf(v.x); o.y = f2bf(v.y); o.z = f2bf(v.z); o.w = f2bf(v.w);
        xb4[i] = o;
    } else {
        int i = (b - CVT_BLOCKS) * 256 + threadIdx.x;
        if (i >= 3 * N_EDGE) return;
        int r = (i >= 2 * N_EDGE) ? 2 : (i >= N_EDGE) ? 1 : 0;
        int e = i - r * N_EDGE;
        const int* d = (r == 0) ? d0 : (r == 1) ? d1 : d2;
        atomicAdd(&rp[r * N_VUL + d[e]], 1);
    }
}

// bf16 gather: 32 lanes per v, ushort4 (4 cols) per lane, 4-way ILP unroll.
__global__ void __launch_bounds__(256) gather3b_kernel(
        const unsigned short* __restrict__ xb,
        const int* __restrict__ rp, const int* __restrict__ ss,
        float* __restrict__ out) {
    int t    = blockIdx.x * blockDim.x + threadIdx.x;
    int v    = t >> 5;
    int lane = t & 31;
    if (v >= N_VUL) return;

    float4 res = make_float4(0.f, 0.f, 0.f, 0.f);
    #pragma unroll
    for (int r = 0; r < 3; ++r) {
        const unsigned short* x = xb + (size_t)r * (N_SRC * DIM);
        int g   = r * N_VUL + v;
        int end = rp[g];
        int beg = (g == 0) ? 0 : rp[g - 1];

        float4 acc = make_float4(0.f, 0.f, 0.f, 0.f);
        for (int base = beg; base < end; base += 32) {
            int j  = base + lane;
            int sv = (j < end) ? ss[j] : 0;
            int m  = end - base;
            if (m > 32) m = 32;
            int k = 0;
            for (; k + 4 <= m; k += 4) {
                int s0 = __shfl(sv, k + 0, 32);
                int s1 = __shfl(sv, k + 1, 32);
                int s2 = __shfl(sv, k + 2, 32);
                int s3 = __shfl(sv, k + 3, 32);
                ushort4 a0 = ((const ushort4*)(x + (size_t)s0 * DIM))[lane];
                ushort4 a1 = ((const ushort4*)(x + (size_t)s1 * DIM))[lane];
                ushort4 a2 = ((const ushort4*)(x + (size_t)s2 * DIM))[lane];
                ushort4 a3 = ((const ushort4*)(x + (size_t)s3 * DIM))[lane];
                acc.x += (bf2f(a0.x) + bf2f(a1.x)) + (bf2f(a2.x) + bf2f(a3.x));
                acc.y += (bf2f(a0.y) + bf2f(a1.y)) + (bf2f(a2.y) + bf2f(a3.y));
                acc.z += (bf2f(a0.z) + bf2f(a1.z)) + (bf2f(a2.z) + bf2f(a3.z));
                acc.w += (bf2f(a0.w) + bf2f(a1.w)) + (bf2f(a2.w) + bf2f(a3.w));
            }
            for (; k < m; ++k) {
                int s0 = __shfl(sv, k, 32);
                ushort4 a0 = ((const ushort4*)(x + (size_t)s0 * DIM))[lane];
                acc.x += bf2f(a0.x); acc.y += bf2f(a0.y);
                acc.z += bf2f(a0.z); acc.w += bf2f(a0.w);
            }
        }
        int deg = end - beg;
        float sc = 1.0f / (3.0f * (float)(deg > 0 ? deg : 1));
        res.x += acc.x * sc; res.y += acc.y * sc;
        res.z += acc.z * sc; res.w += acc.w * sc;
    }

    ((float4*)(out + (size_t)v * DIM))[lane] = res;
}

// ------------------------- TIER B (R3 f32) kernels -------------------------

__global__ void count3_kernel(const int* __restrict__ d0, const int* __restrict__ d1,
                              const int* __restrict__ d2, int* __restrict__ rp) {
    int i = blockIdx.x * blockDim.x + threadIdx.x;
    if (i >= 3 * N_EDGE) return;
    int r = (i >= 2 * N_EDGE) ? 2 : (i >= N_EDGE) ? 1 : 0;
    int e = i - r * N_EDGE;
    const int* d = (r == 0) ? d0 : (r == 1) ? d1 : d2;
    atomicAdd(&rp[r * N_VUL + d[e]], 1);
}

__global__ void gather3_kernel(const float* __restrict__ x0, const float* __restrict__ x1,
                               const float* __restrict__ x2,
                               const int* __restrict__ rp, const int* __restrict__ ss,
                               float* __restrict__ out) {
    int t    = blockIdx.x * blockDim.x + threadIdx.x;
    int v    = t >> 5;
    int lane = t & 31;
    if (v >= N_VUL) return;

    float4 res = make_float4(0.f, 0.f, 0.f, 0.f);
    #pragma unroll
    for (int r = 0; r < 3; ++r) {
        const float* x = (r == 0) ? x0 : (r == 1) ? x1 : x2;
        int g   = r * N_VUL + v;
        int end = rp[g];
        int beg = (g == 0) ? 0 : rp[g - 1];
        float4 acc = make_float4(0.f, 0.f, 0.f, 0.f);
        for (int base = beg; base < end; base += 32) {
            int j  = base + lane;
            int sv = (j < end) ? ss[j] : 0;
            int m  = end - base;
            if (m > 32) m = 32;
            for (int k = 0; k < m; ++k) {
                int s = __shfl(sv, k, 32);
                float4 xv = ((const float4*)(x + (size_t)s * DIM))[lane];
                acc.x += xv.x; acc.y += xv.y; acc.z += xv.z; acc.w += xv.w;
            }
        }
        int deg = end - beg;
        float sc = 1.0f / (3.0f * (float)(deg > 0 ? deg : 1));
        res.x += acc.x * sc; res.y += acc.y * sc;
        res.z += acc.z * sc; res.w += acc.w * sc;
    }
    ((float4*)(out + (size_t)v * DIM))[lane] = res;
}

// ------------------------- TIER C (R2 sequential) --------------------------

__global__ void count_kernel(const int* __restrict__ dst, int* __restrict__ cnt, int n) {
    int i = blockIdx.x * blockDim.x + threadIdx.x;
    if (i < n) atomicAdd(&cnt[dst[i]], 1);
}

__global__ void scan_kernel(int* __restrict__ rp, int n) {
    __shared__ int warp_sums[16];
    __shared__ int s_carry;
    const int tid  = threadIdx.x;
    const int lane = tid & 63;
    const int wid  = tid >> 6;
    if (tid == 0) s_carry = 0;
    __syncthreads();
    for (int base = 0; base < n; base += 4096) {
        int idx = base + tid * 4;
        int4 v = make_int4(0, 0, 0, 0);
        if (idx + 3 < n) v = *(const int4*)(rp + idx);
        else {
            if (idx + 0 < n) v.x = rp[idx + 0];
            if (idx + 1 < n) v.y = rp[idx + 1];
            if (idx + 2 < n) v.z = rp[idx + 2];
            if (idx + 3 < n) v.w = rp[idx + 3];
        }
        int tsum = v.x + v.y + v.z + v.w;
        int s = tsum;
        #pragma unroll
        for (int off = 1; off < 64; off <<= 1) {
            int t = __shfl_up(s, off);
            if (lane >= off) s += t;
        }
        if (lane == 63) warp_sums[wid] = s;
        __syncthreads();
        if (tid < 16) {
            int ws = warp_sums[tid];
            #pragma unroll
            for (int off = 1; off < 16; off <<= 1) {
                int t = __shfl_up(ws, off);
                if (tid >= off) ws += t;
            }
            warp_sums[tid] = ws;
        }
        __syncthreads();
        int carry = s_carry;
        int excl  = s - tsum + (wid > 0 ? warp_sums[wid - 1] : 0) + carry;
        int4 o;
        o.x = excl; o.y = o.x + v.x; o.z = o.y + v.y; o.w = o.z + v.z;
        if (idx + 3 < n) *(int4*)(rp + idx) = o;
        else {
            if (idx + 0 < n) rp[idx + 0] = o.x;
            if (idx + 1 < n) rp[idx + 1] = o.y;
            if (idx + 2 < n) rp[idx + 2] = o.z;
            if (idx + 3 < n) rp[idx + 3] = o.w;
        }
        __syncthreads();
        if (tid == 0) s_carry = carry + warp_sums[15];
        __syncthreads();
    }
}

__global__ void scatter_kernel(const int* __restrict__ src, const int* __restrict__ dst,
                               int* __restrict__ rp, int* __restrict__ ss, int n) {
    int i = blockIdx.x * blockDim.x + threadIdx.x;
    if (i < n) {
        int pos = atomicAdd(&rp[dst[i]], 1);
        ss[pos] = src[i];
    }
}

template <bool ACC>
__global__ void gather_kernel(const float* __restrict__ x, const int* __restrict__ rp,
                              const int* __restrict__ ss, float* __restrict__ out) {
    int t    = blockIdx.x * blockDim.x + threadIdx.x;
    int v    = t >> 5;
    int lane = t & 31;
    if (v >= N_VUL) return;
    int end = rp[v];
    int beg = (v == 0) ? 0 : rp[v - 1];
    float4 acc = make_float4(0.f, 0.f, 0.f, 0.f);
    for (int base = beg; base < end; base += 32) {
        int j  = base + lane;
        int sv = (j < end) ? ss[j] : 0;
        int m  = end - base;
        if (m > 32) m = 32;
        for (int k = 0; k < m; ++k) {
            int s = __shfl(sv, k, 32);
            float4 xv = ((const float4*)(x + (size_t)s * DIM))[lane];
            acc.x += xv.x; acc.y += xv.y; acc.z += xv.z; acc.w += xv.w;
        }
    }
    int deg = end - beg;
    float sc = 1.0f / (3.0f * (float)(deg > 0 ? deg : 1));
    float4 res;
    res.x = acc.x * sc; res.y = acc.y * sc; res.z = acc.z * sc; res.w = acc.w * sc;
    float4* o = (float4*)(out + (size_t)v * DIM) + lane;
    if (ACC) {
        float4 prev = *o;
        res.x += prev.x; res.y += prev.y; res.z += prev.z; res.w += prev.w;
    }
    *o = res;
}

// ---------------------------------------------------------------------------
extern "C" void kernel_launch(void* const* d_in, const int* in_sizes, int n_in,
                              void* d_out, int out_size, void* d_ws, size_t ws_size,
                              hipStream_t stream) {
    const float* x[3]   = { (const float*)d_in[0], (const float*)d_in[1], (const float*)d_in[2] };
    const int*   src[3] = { (const int*)d_in[3],   (const int*)d_in[5],   (const int*)d_in[7] };
    const int*   dst[3] = { (const int*)d_in[4],   (const int*)d_in[6],   (const int*)d_in[8] };
    float* out = (float*)d_out;

    const int B = 256;
    const int n_rp     = 3 * N_VUL;              // 300000
    const int n_chunks = (n_rp + 1023) / 1024;   // 293
    const int n_rp4    = n_rp / 4;               // 75000

    const size_t INT_WS  = (size_t)(n_rp + 3 * N_EDGE + 512) * sizeof(int);      // 7,202,048
    const size_t BF16_WS = INT_WS + (size_t)3 * N_SRC * DIM * sizeof(short);     // +38.4 MB
    const size_t F32_WS  = INT_WS;
    const size_t SEQ_WS  = (size_t)(N_VUL + N_EDGE) * sizeof(int);

    if (ws_size >= BF16_WS) {
        int* rp   = (int*)d_ws;
        int* ss   = rp + n_rp;
        int* bsum = ss + 3 * N_EDGE;
        unsigned short* xb = (unsigned short*)(bsum + 512);   // 8B-aligned

        zero_i_kernel<<<(n_rp + B - 1) / B, B, 0, stream>>>(rp, n_rp);
        count3cvt_kernel<<<CVT_BLOCKS + CNT_BLOCKS, B, 0, stream>>>(
            (const float4*)x[0], (const float4*)x[1], (const float4*)x[2], (ushort4*)xb,
            dst[0], dst[1], dst[2], rp);
        scan_local_kernel<<<n_chunks, B, 0, stream>>>(rp, bsum, n_rp);
        scan_bsum_kernel<<<1, 512, 0, stream>>>(bsum, n_chunks);
        add_off_kernel<<<(n_rp4 + B - 1) / B, B, 0, stream>>>((int4*)rp, bsum, n_rp4);
        scatter3_kernel<<<(3 * N_EDGE + B - 1) / B, B, 0, stream>>>(
            src[0], dst[0], src[1], dst[1], src[2], dst[2], rp, ss);
        gather3b_kernel<<<(N_VUL * 32 + B - 1) / B, B, 0, stream>>>(xb, rp, ss, out);
    } else if (ws_size >= F32_WS) {
        int* rp   = (int*)d_ws;
        int* ss   = rp + n_rp;
        int* bsum = ss + 3 * N_EDGE;

        zero_i_kernel<<<(n_rp + B - 1) / B, B, 0, stream>>>(rp, n_rp);
        count3_kernel<<<(3 * N_EDGE + B - 1) / B, B, 0, stream>>>(dst[0], dst[1], dst[2], rp);
        scan_local_kernel<<<n_chunks, B, 0, stream>>>(rp, bsum, n_rp);
        scan_bsum_kernel<<<1, 512, 0, stream>>>(bsum, n_chunks);
        add_off_kernel<<<(n_rp4 + B - 1) / B, B, 0, stream>>>((int4*)rp, bsum, n_rp4);
        scatter3_kernel<<<(3 * N_EDGE + B - 1) / B, B, 0, stream>>>(
            src[0], dst[0], src[1], dst[1], src[2], dst[2], rp, ss);
        gather3_kernel<<<(N_VUL * 32 + B - 1) / B, B, 0, stream>>>(
            x[0], x[1], x[2], rp, ss, out);
    } else {
        (void)SEQ_WS;
        int* rp = (int*)d_ws;
        int* ss = rp + N_VUL;
        const int g_node = (N_VUL + B - 1) / B;
        const int g_edge = (N_EDGE + B - 1) / B;
        const int g_gath = (N_VUL * 32 + B - 1) / B;
        for (int r = 0; r < 3; ++r) {
            zero_i_kernel<<<g_node, B, 0, stream>>>(rp, N_VUL);
            count_kernel<<<g_edge, B, 0, stream>>>(dst[r], rp, N_EDGE);
            scan_kernel<<<1, 1024, 0, stream>>>(rp, N_VUL);
            scatter_kernel<<<g_edge, B, 0, stream>>>(src[r], dst[r], rp, ss, N_EDGE);
            if (r == 0) gather_kernel<false><<<g_gath, B, 0, stream>>>(x[r], rp, ss, out);
            else        gather_kernel<true ><<<g_gath, B, 0, stream>>>(x[r], rp, ss, out);
        }
    }
}

// Round 5
// 256.256 us; speedup vs baseline: 10.5506x; 1.3944x over previous
//
#include <hip/hip_runtime.h>

#define N_VUL  100000
#define N_SRC  50000
#define N_EDGE 500000
#define DIM    128

// ===========================================================================
// TIER A+ (ws >= 57.7 MB): two-level partition, no global-atomic fine scatter.
//   gcount : 147 ints   coarse bucket counts   (ws[0..147))
//   cbase  : 148 ints   coarse excl scan       (ws[160..308))
//   cursor : 147 ints   partition claim cursors(ws[320..467))
//   rp     : 3*N_VUL    per-(r,dst) bucket ENDs (written by bucket_kernel)
//   ss     : 3*N_EDGE   dst-sorted src ids
//   ss2    : 3*N_EDGE int2  coarse-partitioned (dst|r<<17, src) pairs
//   xb     : 3*N_SRC*DIM ushort  bf16 x
// Coarse bucket: b = r*49 + (dst>>11)  (2048 dsts per bucket, 49 per relation)
// TIER A (ws >= 45.6 MB): R4 path.  TIER B / C: R3 / R2 paths.
// ===========================================================================

#define SHIFT   11
#define NBR     49                              // ceil(N_VUL / 2048)
#define NBT     (3 * NBR)                       // 147
#define PART_E  4096
#define PART_BLOCKS ((3 * N_EDGE + PART_E - 1) / PART_E)   // 367

__device__ __forceinline__ unsigned short f2bf(float f) {
    unsigned u = __float_as_uint(f);
    unsigned r = (u + 0x7FFFu + ((u >> 16) & 1u)) >> 16;   // RNE
    return (unsigned short)r;
}
__device__ __forceinline__ float bf2f(unsigned short h) {
    return __uint_as_float(((unsigned)h) << 16);
}

__global__ void zero_i_kernel(int* __restrict__ p, int n) {
    int i = blockIdx.x * blockDim.x + threadIdx.x;
    if (i < n) p[i] = 0;
}

// ------------------------- TIER A+ kernels ---------------------------------

#define CVT_Q      (N_SRC * DIM / 4)            // 1.6M float4 per relation
#define CVT_BLOCKS (3 * CVT_Q / 256)            // 18750 (exact)
#define CH_BLOCKS  PART_BLOCKS                  // 367 coarse-hist blocks

// Heterogeneous: blocks [0,CVT_BLOCKS) convert f32->bf16; the rest build the
// 147-entry coarse histogram via per-block LDS hist (no hot global atomics).
__global__ void cvt_chist_kernel(const float4* __restrict__ x0, const float4* __restrict__ x1,
                                 const float4* __restrict__ x2, ushort4* __restrict__ xb4,
                                 const int* __restrict__ d0, const int* __restrict__ d1,
                                 const int* __restrict__ d2, int* __restrict__ gcount) {
    __shared__ int lh[NBT];
    int b = blockIdx.x;
    if (b < CVT_BLOCKS) {
        int i = b * 256 + threadIdx.x;
        int r = i / CVT_Q;
        int e = i - r * CVT_Q;
        float4 v = ((r == 0) ? x0 : (r == 1) ? x1 : x2)[e];
        ushort4 o;
        o.x = f2bf(v.x); o.y = f2bf(v.y); o.z = f2bf(v.z); o.w = f2bf(v.w);
        xb4[i] = o;
    } else {
        int tid = threadIdx.x;
        for (int j = tid; j < NBT; j += 256) lh[j] = 0;
        __syncthreads();
        int e0 = (b - CVT_BLOCKS) * PART_E;
        #pragma unroll
        for (int k = 0; k < PART_E / 256; ++k) {
            int i = e0 + k * 256 + tid;
            if (i < 3 * N_EDGE) {
                int r = (i >= 2 * N_EDGE) ? 2 : (i >= N_EDGE) ? 1 : 0;
                int e = i - r * N_EDGE;
                const int* dp = (r == 0) ? d0 : (r == 1) ? d1 : d2;
                int d = dp[e];
                atomicAdd(&lh[r * NBR + (d >> SHIFT)], 1);
            }
        }
        __syncthreads();
        for (int j = tid; j < NBT; j += 256)
            if (lh[j]) atomicAdd(&gcount[j], lh[j]);
    }
}

// Exclusive scan of gcount[147] -> cbase[148]; cursor = cbase.
__global__ void cscan_kernel(const int* __restrict__ gcount, int* __restrict__ cbase,
                             int* __restrict__ cursor) {
    int tid = threadIdx.x;
    if (tid == 0) {
        int run = 0;
        for (int b = 0; b < NBT; ++b) { cbase[b] = run; run += gcount[b]; }
        cbase[NBT] = run;
    }
    __syncthreads();
    if (tid < NBT) cursor[tid] = cbase[tid];
}

// Partition edges into 147 coarse buckets; LDS-sorted staging so global
// writes go out as contiguous per-bucket runs (~224 B average).
__global__ void __launch_bounds__(256) partition_kernel(
        const int* __restrict__ s0, const int* __restrict__ d0,
        const int* __restrict__ s1, const int* __restrict__ d1,
        const int* __restrict__ s2, const int* __restrict__ d2,
        int* __restrict__ cursor, int2* __restrict__ ss2) {
    __shared__ int  hist[NBT];
    __shared__ int  lbase[NBT];
    __shared__ int  gbase[NBT];
    __shared__ int  s_vtot;
    __shared__ int2 stage[PART_E];          // 32 KB

    const int tid = threadIdx.x;
    for (int j = tid; j < NBT; j += 256) hist[j] = 0;
    __syncthreads();

    const int e0 = blockIdx.x * PART_E;
    int myx[PART_E / 256], mys[PART_E / 256], myrank[PART_E / 256];
    #pragma unroll
    for (int k = 0; k < PART_E / 256; ++k) {
        int i = e0 + k * 256 + tid;
        if (i < 3 * N_EDGE) {
            int r = (i >= 2 * N_EDGE) ? 2 : (i >= N_EDGE) ? 1 : 0;
            int e = i - r * N_EDGE;
            const int* sp = (r == 0) ? s0 : (r == 1) ? s1 : s2;
            const int* dp = (r == 0) ? d0 : (r == 1) ? d1 : d2;
            int d = dp[e];
            int bkt = r * NBR + (d >> SHIFT);
            myrank[k] = atomicAdd(&hist[bkt], 1);
            myx[k] = d | (r << 17);
            mys[k] = sp[e];
        } else {
            myx[k] = -1;
        }
    }
    __syncthreads();

    if (tid == 0) {
        int run = 0;
        for (int b = 0; b < NBT; ++b) { lbase[b] = run; run += hist[b]; }
        s_vtot = run;
    }
    __syncthreads();
    if (tid < NBT && hist[tid] > 0)
        gbase[tid] = atomicAdd(&cursor[tid], hist[tid]);
    __syncthreads();

    #pragma unroll
    for (int k = 0; k < PART_E / 256; ++k) {
        if (myx[k] >= 0) {
            int r = myx[k] >> 17;
            int bkt = r * NBR + ((myx[k] & 0x1FFFF) >> SHIFT);
            stage[lbase[bkt] + myrank[k]] = make_int2(myx[k], mys[k]);
        }
    }
    __syncthreads();

    const int vtot = s_vtot;
    for (int j = tid; j < vtot; j += 256) {
        int2 p = stage[j];
        int r = p.x >> 17;
        int bkt = r * NBR + ((p.x & 0x1FFFF) >> SHIFT);
        ss2[gbase[bkt] + (j - lbase[bkt])] = p;
    }
}

// One block per coarse bucket: LDS histogram over its 2048 dsts -> in-block
// scan -> LDS-cursor fine scatter (ss writes are XCD-local) + rp ENDs.
__global__ void __launch_bounds__(256) bucket_kernel(
        const int2* __restrict__ ss2, const int* __restrict__ cbase,
        int* __restrict__ rp, int* __restrict__ ss) {
    __shared__ int hist[1 << SHIFT];        // 2048 ints
    __shared__ int wsum[4];

    const int tid = threadIdx.x;
    const int b   = blockIdx.x;             // 0..146
    const int r   = b / NBR;
    const int c   = b - r * NBR;
    const int dbase  = c << SHIFT;
    int dcount = N_VUL - dbase; if (dcount > (1 << SHIFT)) dcount = 1 << SHIFT;

    const int beg = cbase[b];
    const int end = cbase[b + 1];
    const int nE  = end - beg;

    for (int j = tid; j < (1 << SHIFT); j += 256) hist[j] = 0;
    __syncthreads();

    // sweep 1: count
    for (int j = tid; j < nE; j += 256) {
        int2 p = ss2[beg + j];
        atomicAdd(&hist[(p.x & 0x1FFFF) - dbase], 1);
    }
    __syncthreads();

    // in-block exclusive scan of hist[2048]; hist becomes per-dst START
    int vals[8]; int tsum = 0;
    #pragma unroll
    for (int k = 0; k < 8; ++k) { vals[k] = hist[tid * 8 + k]; tsum += vals[k]; }
    int s = tsum;
    const int lane = tid & 63, wid = tid >> 6;
    #pragma unroll
    for (int off = 1; off < 64; off <<= 1) {
        int t = __shfl_up(s, off);
        if (lane >= off) s += t;
    }
    if (lane == 63) wsum[wid] = s;
    __syncthreads();
    if (tid == 0) {
        int a = 0;
        #pragma unroll
        for (int j = 0; j < 4; ++j) { int t = wsum[j]; wsum[j] = a; a += t; }
    }
    __syncthreads();
    int run = (s - tsum) + wsum[wid];
    #pragma unroll
    for (int k = 0; k < 8; ++k) { hist[tid * 8 + k] = run; run += vals[k]; }
    __syncthreads();

    // sweep 2: fine scatter via LDS cursors (hist becomes per-dst END)
    for (int j = tid; j < nE; j += 256) {
        int2 p = ss2[beg + j];
        int pos = atomicAdd(&hist[(p.x & 0x1FFFF) - dbase], 1);
        ss[beg + pos] = p.y;
    }
    __syncthreads();

    // rp ends (global cumulative, consistent with gather contract)
    for (int t = tid; t < dcount; t += 256)
        rp[r * N_VUL + dbase + t] = beg + hist[t];
}

// bf16 gather: 32 lanes per v, ushort4 per lane, 4-way ILP unroll.
__global__ void __launch_bounds__(256) gather3b_kernel(
        const unsigned short* __restrict__ xb,
        const int* __restrict__ rp, const int* __restrict__ ss,
        float* __restrict__ out) {
    int t    = blockIdx.x * blockDim.x + threadIdx.x;
    int v    = t >> 5;
    int lane = t & 31;
    if (v >= N_VUL) return;

    float4 res = make_float4(0.f, 0.f, 0.f, 0.f);
    #pragma unroll
    for (int r = 0; r < 3; ++r) {
        const unsigned short* x = xb + (size_t)r * (N_SRC * DIM);
        int g   = r * N_VUL + v;
        int end = rp[g];
        int beg = (g == 0) ? 0 : rp[g - 1];

        float4 acc = make_float4(0.f, 0.f, 0.f, 0.f);
        for (int base = beg; base < end; base += 32) {
            int j  = base + lane;
            int sv = (j < end) ? ss[j] : 0;
            int m  = end - base;
            if (m > 32) m = 32;
            int k = 0;
            for (; k + 4 <= m; k += 4) {
                int s0 = __shfl(sv, k + 0, 32);
                int s1 = __shfl(sv, k + 1, 32);
                int s2 = __shfl(sv, k + 2, 32);
                int s3 = __shfl(sv, k + 3, 32);
                ushort4 a0 = ((const ushort4*)(x + (size_t)s0 * DIM))[lane];
                ushort4 a1 = ((const ushort4*)(x + (size_t)s1 * DIM))[lane];
                ushort4 a2 = ((const ushort4*)(x + (size_t)s2 * DIM))[lane];
                ushort4 a3 = ((const ushort4*)(x + (size_t)s3 * DIM))[lane];
                acc.x += (bf2f(a0.x) + bf2f(a1.x)) + (bf2f(a2.x) + bf2f(a3.x));
                acc.y += (bf2f(a0.y) + bf2f(a1.y)) + (bf2f(a2.y) + bf2f(a3.y));
                acc.z += (bf2f(a0.z) + bf2f(a1.z)) + (bf2f(a2.z) + bf2f(a3.z));
                acc.w += (bf2f(a0.w) + bf2f(a1.w)) + (bf2f(a2.w) + bf2f(a3.w));
            }
            for (; k < m; ++k) {
                int s0 = __shfl(sv, k, 32);
                ushort4 a0 = ((const ushort4*)(x + (size_t)s0 * DIM))[lane];
                acc.x += bf2f(a0.x); acc.y += bf2f(a0.y);
                acc.z += bf2f(a0.z); acc.w += bf2f(a0.w);
            }
        }
        int deg = end - beg;
        float sc = 1.0f / (3.0f * (float)(deg > 0 ? deg : 1));
        res.x += acc.x * sc; res.y += acc.y * sc;
        res.z += acc.z * sc; res.w += acc.w * sc;
    }

    ((float4*)(out + (size_t)v * DIM))[lane] = res;
}

// ------------------------- TIER A (R4) kernels -----------------------------

__global__ void scan_local_kernel(int* __restrict__ rp, int* __restrict__ bsum, int n) {
    __shared__ int wsum[4];
    const int tid  = threadIdx.x;
    const int lane = tid & 63;
    const int wid  = tid >> 6;
    int idx = blockIdx.x * 1024 + tid * 4;
    int4 v = make_int4(0, 0, 0, 0);
    if (idx + 3 < n)      v = *(const int4*)(rp + idx);
    else {
        if (idx + 0 < n) v.x = rp[idx + 0];
        if (idx + 1 < n) v.y = rp[idx + 1];
        if (idx + 2 < n) v.z = rp[idx + 2];
        if (idx + 3 < n) v.w = rp[idx + 3];
    }
    int tsum = v.x + v.y + v.z + v.w;
    int s = tsum;
    #pragma unroll
    for (int off = 1; off < 64; off <<= 1) {
        int t = __shfl_up(s, off);
        if (lane >= off) s += t;
    }
    if (lane == 63) wsum[wid] = s;
    __syncthreads();
    if (tid == 0) {
        int a = 0;
        #pragma unroll
        for (int j = 0; j < 4; ++j) { int t = wsum[j]; wsum[j] = a; a += t; }
        bsum[blockIdx.x] = a;
    }
    __syncthreads();
    int excl = (s - tsum) + wsum[wid];
    int4 o;
    o.x = excl; o.y = o.x + v.x; o.z = o.y + v.y; o.w = o.z + v.z;
    if (idx + 3 < n)      *(int4*)(rp + idx) = o;
    else {
        if (idx + 0 < n) rp[idx + 0] = o.x;
        if (idx + 1 < n) rp[idx + 1] = o.y;
        if (idx + 2 < n) rp[idx + 2] = o.z;
        if (idx + 3 < n) rp[idx + 3] = o.w;
    }
}

__global__ void scan_bsum_kernel(int* __restrict__ bsum, int nb) {
    __shared__ int sh[512];
    int tid = threadIdx.x;
    int v = (tid < nb) ? bsum[tid] : 0;
    sh[tid] = v;
    __syncthreads();
    #pragma unroll
    for (int off = 1; off < 512; off <<= 1) {
        int t = 0;
        if (tid >= off) t = sh[tid - off];
        __syncthreads();
        sh[tid] += t;
        __syncthreads();
    }
    if (tid < nb) bsum[tid] = sh[tid] - v;
}

__global__ void add_off_kernel(int4* __restrict__ rp4, const int* __restrict__ bsum, int n4) {
    int i = blockIdx.x * blockDim.x + threadIdx.x;
    if (i >= n4) return;
    int off = bsum[i >> 8];
    int4 v = rp4[i];
    v.x += off; v.y += off; v.z += off; v.w += off;
    rp4[i] = v;
}

__global__ void scatter3_kernel(const int* __restrict__ s0, const int* __restrict__ d0,
                                const int* __restrict__ s1, const int* __restrict__ d1,
                                const int* __restrict__ s2, const int* __restrict__ d2,
                                int* __restrict__ rp, int* __restrict__ ss) {
    int i = blockIdx.x * blockDim.x + threadIdx.x;
    if (i >= 3 * N_EDGE) return;
    int r = (i >= 2 * N_EDGE) ? 2 : (i >= N_EDGE) ? 1 : 0;
    int e = i - r * N_EDGE;
    const int* sp = (r == 0) ? s0 : (r == 1) ? s1 : s2;
    const int* dp = (r == 0) ? d0 : (r == 1) ? d1 : d2;
    int pos = atomicAdd(&rp[r * N_VUL + dp[e]], 1);
    ss[pos] = sp[e];
}

__global__ void count3cvt_kernel(const float4* __restrict__ x0, const float4* __restrict__ x1,
                                 const float4* __restrict__ x2, ushort4* __restrict__ xb4,
                                 const int* __restrict__ d0, const int* __restrict__ d1,
                                 const int* __restrict__ d2, int* __restrict__ rp) {
    int b = blockIdx.x;
    if (b < CVT_BLOCKS) {
        int i = b * 256 + threadIdx.x;
        int r = i / CVT_Q;
        int e = i - r * CVT_Q;
        float4 v = ((r == 0) ? x0 : (r == 1) ? x1 : x2)[e];
        ushort4 o;
        o.x = f2bf(v.x); o.y = f2bf(v.y); o.z = f2bf(v.z); o.w = f2bf(v.w);
        xb4[i] = o;
    } else {
        int i = (b - CVT_BLOCKS) * 256 + threadIdx.x;
        if (i >= 3 * N_EDGE) return;
        int r = (i >= 2 * N_EDGE) ? 2 : (i >= N_EDGE) ? 1 : 0;
        int e = i - r * N_EDGE;
        const int* d = (r == 0) ? d0 : (r == 1) ? d1 : d2;
        atomicAdd(&rp[r * N_VUL + d[e]], 1);
    }
}

// ------------------------- TIER B / C kernels ------------------------------

__global__ void count3_kernel(const int* __restrict__ d0, const int* __restrict__ d1,
                              const int* __restrict__ d2, int* __restrict__ rp) {
    int i = blockIdx.x * blockDim.x + threadIdx.x;
    if (i >= 3 * N_EDGE) return;
    int r = (i >= 2 * N_EDGE) ? 2 : (i >= N_EDGE) ? 1 : 0;
    int e = i - r * N_EDGE;
    const int* d = (r == 0) ? d0 : (r == 1) ? d1 : d2;
    atomicAdd(&rp[r * N_VUL + d[e]], 1);
}

__global__ void gather3_kernel(const float* __restrict__ x0, const float* __restrict__ x1,
                               const float* __restrict__ x2,
                               const int* __restrict__ rp, const int* __restrict__ ss,
                               float* __restrict__ out) {
    int t    = blockIdx.x * blockDim.x + threadIdx.x;
    int v    = t >> 5;
    int lane = t & 31;
    if (v >= N_VUL) return;
    float4 res = make_float4(0.f, 0.f, 0.f, 0.f);
    #pragma unroll
    for (int r = 0; r < 3; ++r) {
        const float* x = (r == 0) ? x0 : (r == 1) ? x1 : x2;
        int g   = r * N_VUL + v;
        int end = rp[g];
        int beg = (g == 0) ? 0 : rp[g - 1];
        float4 acc = make_float4(0.f, 0.f, 0.f, 0.f);
        for (int base = beg; base < end; base += 32) {
            int j  = base + lane;
            int sv = (j < end) ? ss[j] : 0;
            int m  = end - base;
            if (m > 32) m = 32;
            for (int k = 0; k < m; ++k) {
                int s = __shfl(sv, k, 32);
                float4 xv = ((const float4*)(x + (size_t)s * DIM))[lane];
                acc.x += xv.x; acc.y += xv.y; acc.z += xv.z; acc.w += xv.w;
            }
        }
        int deg = end - beg;
        float sc = 1.0f / (3.0f * (float)(deg > 0 ? deg : 1));
        res.x += acc.x * sc; res.y += acc.y * sc;
        res.z += acc.z * sc; res.w += acc.w * sc;
    }
    ((float4*)(out + (size_t)v * DIM))[lane] = res;
}

__global__ void count_kernel(const int* __restrict__ dst, int* __restrict__ cnt, int n) {
    int i = blockIdx.x * blockDim.x + threadIdx.x;
    if (i < n) atomicAdd(&cnt[dst[i]], 1);
}

__global__ void scan_kernel(int* __restrict__ rp, int n) {
    __shared__ int warp_sums[16];
    __shared__ int s_carry;
    const int tid  = threadIdx.x;
    const int lane = tid & 63;
    const int wid  = tid >> 6;
    if (tid == 0) s_carry = 0;
    __syncthreads();
    for (int base = 0; base < n; base += 4096) {
        int idx = base + tid * 4;
        int4 v = make_int4(0, 0, 0, 0);
        if (idx + 3 < n) v = *(const int4*)(rp + idx);
        else {
            if (idx + 0 < n) v.x = rp[idx + 0];
            if (idx + 1 < n) v.y = rp[idx + 1];
            if (idx + 2 < n) v.z = rp[idx + 2];
            if (idx + 3 < n) v.w = rp[idx + 3];
        }
        int tsum = v.x + v.y + v.z + v.w;
        int s = tsum;
        #pragma unroll
        for (int off = 1; off < 64; off <<= 1) {
            int t = __shfl_up(s, off);
            if (lane >= off) s += t;
        }
        if (lane == 63) warp_sums[wid] = s;
        __syncthreads();
        if (tid < 16) {
            int ws = warp_sums[tid];
            #pragma unroll
            for (int off = 1; off < 16; off <<= 1) {
                int t = __shfl_up(ws, off);
                if (tid >= off) ws += t;
            }
            warp_sums[tid] = ws;
        }
        __syncthreads();
        int carry = s_carry;
        int excl  = s - tsum + (wid > 0 ? warp_sums[wid - 1] : 0) + carry;
        int4 o;
        o.x = excl; o.y = o.x + v.x; o.z = o.y + v.y; o.w = o.z + v.z;
        if (idx + 3 < n) *(int4*)(rp + idx) = o;
        else {
            if (idx + 0 < n) rp[idx + 0] = o.x;
            if (idx + 1 < n) rp[idx + 1] = o.y;
            if (idx + 2 < n) rp[idx + 2] = o.z;
            if (idx + 3 < n) rp[idx + 3] = o.w;
        }
        __syncthreads();
        if (tid == 0) s_carry = carry + warp_sums[15];
        __syncthreads();
    }
}

__global__ void scatter_kernel(const int* __restrict__ src, const int* __restrict__ dst,
                               int* __restrict__ rp, int* __restrict__ ss, int n) {
    int i = blockIdx.x * blockDim.x + threadIdx.x;
    if (i < n) {
        int pos = atomicAdd(&rp[dst[i]], 1);
        ss[pos] = src[i];
    }
}

template <bool ACC>
__global__ void gather_kernel(const float* __restrict__ x, const int* __restrict__ rp,
                              const int* __restrict__ ss, float* __restrict__ out) {
    int t    = blockIdx.x * blockDim.x + threadIdx.x;
    int v    = t >> 5;
    int lane = t & 31;
    if (v >= N_VUL) return;
    int end = rp[v];
    int beg = (v == 0) ? 0 : rp[v - 1];
    float4 acc = make_float4(0.f, 0.f, 0.f, 0.f);
    for (int base = beg; base < end; base += 32) {
        int j  = base + lane;
        int sv = (j < end) ? ss[j] : 0;
        int m  = end - base;
        if (m > 32) m = 32;
        for (int k = 0; k < m; ++k) {
            int s = __shfl(sv, k, 32);
            float4 xv = ((const float4*)(x + (size_t)s * DIM))[lane];
            acc.x += xv.x; acc.y += xv.y; acc.z += xv.z; acc.w += xv.w;
        }
    }
    int deg = end - beg;
    float sc = 1.0f / (3.0f * (float)(deg > 0 ? deg : 1));
    float4 res;
    res.x = acc.x * sc; res.y = acc.y * sc; res.z = acc.z * sc; res.w = acc.w * sc;
    float4* o = (float4*)(out + (size_t)v * DIM) + lane;
    if (ACC) {
        float4 prev = *o;
        res.x += prev.x; res.y += prev.y; res.z += prev.z; res.w += prev.w;
    }
    *o = res;
}

// ---------------------------------------------------------------------------
extern "C" void kernel_launch(void* const* d_in, const int* in_sizes, int n_in,
                              void* d_out, int out_size, void* d_ws, size_t ws_size,
                              hipStream_t stream) {
    const float* x[3]   = { (const float*)d_in[0], (const float*)d_in[1], (const float*)d_in[2] };
    const int*   src[3] = { (const int*)d_in[3],   (const int*)d_in[5],   (const int*)d_in[7] };
    const int*   dst[3] = { (const int*)d_in[4],   (const int*)d_in[6],   (const int*)d_in[8] };
    float* out = (float*)d_out;

    const int B = 256;
    const int n_rp     = 3 * N_VUL;
    const int n_chunks = (n_rp + 1023) / 1024;
    const int n_rp4    = n_rp / 4;

    // Tier A+ layout (ints): [0..147) gcount | [160..308) cbase | [320..467) cursor
    //   | [512..300512) rp | [300512..1800512) ss | [1800512..4800512) ss2 | xb
    const size_t AP_INTS = 512 + (size_t)n_rp + 3 * N_EDGE + 2 * (3 * N_EDGE);
    const size_t AP_WS   = AP_INTS * 4 + (size_t)3 * N_SRC * DIM * sizeof(short); // ~57.6 MB
    const size_t INT_WS  = (size_t)(n_rp + 3 * N_EDGE + 512) * sizeof(int);       // 7.2 MB
    const size_t BF16_WS = INT_WS + (size_t)3 * N_SRC * DIM * sizeof(short);      // 45.6 MB

    if (ws_size >= AP_WS) {
        int*  gcount = (int*)d_ws;
        int*  cbase  = gcount + 160;
        int*  cursor = gcount + 320;
        int*  rp     = gcount + 512;
        int*  ss     = rp + n_rp;
        int2* ss2    = (int2*)(ss + 3 * N_EDGE);
        unsigned short* xb = (unsigned short*)(ss2 + 3 * N_EDGE);

        zero_i_kernel<<<2, B, 0, stream>>>(gcount, 512);
        cvt_chist_kernel<<<CVT_BLOCKS + CH_BLOCKS, B, 0, stream>>>(
            (const float4*)x[0], (const float4*)x[1], (const float4*)x[2], (ushort4*)xb,
            dst[0], dst[1], dst[2], gcount);
        cscan_kernel<<<1, B, 0, stream>>>(gcount, cbase, cursor);
        partition_kernel<<<PART_BLOCKS, B, 0, stream>>>(
            src[0], dst[0], src[1], dst[1], src[2], dst[2], cursor, ss2);
        bucket_kernel<<<NBT, B, 0, stream>>>(ss2, cbase, rp, ss);
        gather3b_kernel<<<(N_VUL * 32 + B - 1) / B, B, 0, stream>>>(xb, rp, ss, out);
    } else if (ws_size >= BF16_WS) {
        int* rp   = (int*)d_ws;
        int* ss   = rp + n_rp;
        int* bsum = ss + 3 * N_EDGE;
        unsigned short* xb = (unsigned short*)(bsum + 512);

        zero_i_kernel<<<(n_rp + B - 1) / B, B, 0, stream>>>(rp, n_rp);
        count3cvt_kernel<<<CVT_BLOCKS + (3 * N_EDGE + B - 1) / B, B, 0, stream>>>(
            (const float4*)x[0], (const float4*)x[1], (const float4*)x[2], (ushort4*)xb,
            dst[0], dst[1], dst[2], rp);
        scan_local_kernel<<<n_chunks, B, 0, stream>>>(rp, bsum, n_rp);
        scan_bsum_kernel<<<1, 512, 0, stream>>>(bsum, n_chunks);
        add_off_kernel<<<(n_rp4 + B - 1) / B, B, 0, stream>>>((int4*)rp, bsum, n_rp4);
        scatter3_kernel<<<(3 * N_EDGE + B - 1) / B, B, 0, stream>>>(
            src[0], dst[0], src[1], dst[1], src[2], dst[2], rp, ss);
        gather3b_kernel<<<(N_VUL * 32 + B - 1) / B, B, 0, stream>>>(xb, rp, ss, out);
    } else if (ws_size >= INT_WS) {
        int* rp   = (int*)d_ws;
        int* ss   = rp + n_rp;
        int* bsum = ss + 3 * N_EDGE;

        zero_i_kernel<<<(n_rp + B - 1) / B, B, 0, stream>>>(rp, n_rp);
        count3_kernel<<<(3 * N_EDGE + B - 1) / B, B, 0, stream>>>(dst[0], dst[1], dst[2], rp);
        scan_local_kernel<<<n_chunks, B, 0, stream>>>(rp, bsum, n_rp);
        scan_bsum_kernel<<<1, 512, 0, stream>>>(bsum, n_chunks);
        add_off_kernel<<<(n_rp4 + B - 1) / B, B, 0, stream>>>((int4*)rp, bsum, n_rp4);
        scatter3_kernel<<<(3 * N_EDGE + B - 1) / B, B, 0, stream>>>(
            src[0], dst[0], src[1], dst[1], src[2], dst[2], rp, ss);
        gather3_kernel<<<(N_VUL * 32 + B - 1) / B, B, 0, stream>>>(
            x[0], x[1], x[2], rp, ss, out);
    } else {
        int* rp = (int*)d_ws;
        int* ss = rp + N_VUL;
        const int g_node = (N_VUL + B - 1) / B;
        const int g_edge = (N_EDGE + B - 1) / B;
        const int g_gath = (N_VUL * 32 + B - 1) / B;
        for (int r = 0; r < 3; ++r) {
            zero_i_kernel<<<g_node, B, 0, stream>>>(rp, N_VUL);
            count_kernel<<<g_edge, B, 0, stream>>>(dst[r], rp, N_EDGE);
            scan_kernel<<<1, 1024, 0, stream>>>(rp, N_VUL);
            scatter_kernel<<<g_edge, B, 0, stream>>>(src[r], dst[r], rp, ss, N_EDGE);
            if (r == 0) gather_kernel<false><<<g_gath, B, 0, stream>>>(x[r], rp, ss, out);
            else        gather_kernel<true ><<<g_gath, B, 0, stream>>>(x[r], rp, ss, out);
        }
    }
}